// Round 8
// baseline (466.646 us; speedup 1.0000x reference)
//
#include <hip/hip_runtime.h>
#include <hip/hip_bf16.h>

typedef float    f32x4 __attribute__((ext_vector_type(4)));
typedef _Float16 f16x8 __attribute__((ext_vector_type(8)));
typedef unsigned int u32;

#define S_LEN 1024
#define NHEAD 32
#define DHEAD 128
#define HID   4096   // NHEAD*DHEAD
#define LORA  512    // H*R
#define MROWS 2048   // B*S

__device__ __forceinline__ void gload16(const void* g, const void* l) {
  __builtin_amdgcn_global_load_lds(
      (const __attribute__((address_space(1))) u32*)g,
      (__attribute__((address_space(3))) u32*)l, 16, 0, 0);
}

// plain RNE f32->f16 (v_cvt_f16_f32) — validated numerics (round-4 path)
__device__ __forceinline__ f16x8 cvt8(f32x4 a, f32x4 b) {
  f16x8 r;
  r[0] = (_Float16)a[0]; r[1] = (_Float16)a[1];
  r[2] = (_Float16)a[2]; r[3] = (_Float16)a[3];
  r[4] = (_Float16)b[0]; r[5] = (_Float16)b[1];
  r[6] = (_Float16)b[2]; r[7] = (_Float16)b[3];
  return r;
}

// ---------------------------------------------------------------------------
// K1: split-K GEMM  U_partial = X @ Wa^T, reading f32 X (gather-transposed on
// the fly) and f32 Wa, converting in-register during staging.  128x128 tile,
// BK=32, double-buffered LDS, ONE barrier per K-step, next-tile loads issued
// after the barrier (overlap with ds_read+MFMA).  z = side*4+ks.
// ---------------------------------------------------------------------------
__global__ __launch_bounds__(256) void gemm1_kernel(
    const float* __restrict__ Xq, const float* __restrict__ Wqa_,
    const float* __restrict__ Xk, const float* __restrict__ Wka_,
    float* __restrict__ Up)
{
  const int side = blockIdx.z >> 2, ks = blockIdx.z & 3;
  const float* X = side ? Xk : Xq;
  const float* W = side ? Wka_ : Wqa_;
  float* U = Up + ((size_t)(side * 4 + ks)) * (MROWS * LORA);

  __shared__ _Float16 As[2][128 * 32];
  __shared__ _Float16 Bs[2][128 * 32];

  const int t = threadIdx.x, lane = t & 63, w = t >> 6;
  const int wr = w >> 1, wc = w & 1;
  const int m0 = blockIdx.x * 128, n0 = blockIdx.y * 128;
  const int kbeg = ks * 1024;

  // staging map: thread -> (row ar, 16 cols at ac) for both A and B tiles
  const int ar = t >> 1, ac = (t & 1) * 16;
  const int am = m0 + ar, ab = am >> 10, as_ = am & 1023;
  const float* Abase = X + (size_t)ab * (NHEAD * S_LEN * DHEAD) + (size_t)as_ * DHEAD;
  const float* Brow = W + (size_t)(n0 + ar) * HID;

  f16x8 ha0, ha1, hb0, hb1;
  auto LOADREGS = [&](int kt) {
    const int kg = kt + ac;
    const float* pa = Abase + (size_t)(kg >> 7) * (S_LEN * DHEAD) + (kg & 127);
    f32x4 a0 = *(const f32x4*)(pa + 0), a1 = *(const f32x4*)(pa + 4);
    f32x4 a2 = *(const f32x4*)(pa + 8), a3 = *(const f32x4*)(pa + 12);
    const float* pb = Brow + kg;
    f32x4 b0 = *(const f32x4*)(pb + 0), b1 = *(const f32x4*)(pb + 4);
    f32x4 b2 = *(const f32x4*)(pb + 8), b3 = *(const f32x4*)(pb + 12);
    ha0 = cvt8(a0, a1); ha1 = cvt8(a2, a3);
    hb0 = cvt8(b0, b1); hb1 = cvt8(b2, b3);
  };

  LOADREGS(kbeg);
  f32x4 acc[4][4] = {};

  for (int step = 0; step < 32; ++step) {
    const int cur = step & 1;
    // write buf[cur]: its last readers were step-2, drained at step-1's barrier
    *(f16x8*)&As[cur][ar * 32 + ac]     = ha0;
    *(f16x8*)&As[cur][ar * 32 + ac + 8] = ha1;
    *(f16x8*)&Bs[cur][ar * 32 + ac]     = hb0;
    *(f16x8*)&Bs[cur][ar * 32 + ac + 8] = hb1;
    __syncthreads();
    if (step + 1 < 32) LOADREGS(kbeg + (step + 1) * 32);  // overlaps MFMA below
    f16x8 af[4], bf[4];
#pragma unroll
    for (int im = 0; im < 4; ++im)
      af[im] = *(const f16x8*)&As[cur][(wr * 64 + im * 16 + (lane & 15)) * 32 + (lane >> 4) * 8];
#pragma unroll
    for (int in = 0; in < 4; ++in)
      bf[in] = *(const f16x8*)&Bs[cur][(wc * 64 + in * 16 + (lane & 15)) * 32 + (lane >> 4) * 8];
#pragma unroll
    for (int im = 0; im < 4; ++im)
#pragma unroll
      for (int in = 0; in < 4; ++in)
        acc[im][in] = __builtin_amdgcn_mfma_f32_16x16x32_f16(af[im], bf[in], acc[im][in], 0, 0, 0);
  }

#pragma unroll
  for (int im = 0; im < 4; ++im)
#pragma unroll
    for (int in = 0; in < 4; ++in)
#pragma unroll
      for (int j = 0; j < 4; ++j) {
        const int m = m0 + wr * 64 + im * 16 + (lane >> 4) * 4 + j;
        const int n = n0 + wc * 64 + in * 16 + (lane & 15);
        U[(size_t)m * LORA + n] = acc[im][in][j];
      }
}

// ---------------------------------------------------------------------------
// K1b: reduce 4 f32 partials -> f16 U.
// ---------------------------------------------------------------------------
__global__ __launch_bounds__(256) void reduce_u(
    const float* __restrict__ Up, _Float16* __restrict__ Uq, _Float16* __restrict__ Uk)
{
  const int idx = blockIdx.x * 256 + threadIdx.x;   // 8-elem chunk
  const int side = idx >> 17;
  const int cc = idx & 131071;
  const float* base = Up + (size_t)side * 4 * (MROWS * LORA) + (size_t)cc * 8;
  f32x4 s0 = {0.f,0.f,0.f,0.f}, s1 = {0.f,0.f,0.f,0.f};
#pragma unroll
  for (int p = 0; p < 4; ++p) {
    const float* pp = base + (size_t)p * (MROWS * LORA);
    s0 += *(const f32x4*)(pp);
    s1 += *(const f32x4*)(pp + 4);
  }
  f16x8 h;
#pragma unroll
  for (int i = 0; i < 4; ++i) { h[i] = (_Float16)s0[i]; h[i + 4] = (_Float16)s1[i]; }
  _Float16* U = side ? Uk : Uq;
  *(f16x8*)(U + (size_t)cc * 8) = h;
}

// ---------------------------------------------------------------------------
// K2: P = U @ Wb^T.  A-side: f16 U via global_load_lds (issued one step
// ahead, drained at the next barrier).  B-side: f32 Wb reg-staged + RNE cvt.
// Single barrier per K-step, double-buffered.
// ---------------------------------------------------------------------------
__global__ __launch_bounds__(256) void gemm2_kernel(
    const _Float16* __restrict__ Uq, const float* __restrict__ Wqb_,
    const _Float16* __restrict__ Uk, const float* __restrict__ Wkb_,
    _Float16* __restrict__ Pq, _Float16* __restrict__ Pk)
{
  const _Float16* A = blockIdx.z ? Uk : Uq;
  const float*   Wf = blockIdx.z ? Wkb_ : Wqb_;
  _Float16*       P = blockIdx.z ? Pk : Pq;

  __shared__ _Float16 As[2][128 * 32];
  __shared__ _Float16 Bs[2][128 * 32];

  const int t = threadIdx.x, lane = t & 63, w = t >> 6;
  const int wr = w >> 1, wc = w & 1;
  const int m0 = blockIdx.x * 128, n0 = blockIdx.y * 128;

  // A gload_lds slots (16B per thread x2 across the 8 KB tile)
  const int o0 = w * 1024 + lane * 16;
  const int o1 = o0 + 4096;
  const int r0 = o0 >> 6, k0e = (o0 & 63) >> 1;
  const int r1 = o1 >> 6, k1e = (o1 & 63) >> 1;

  // B staging map
  const int ar = t >> 1, ac = (t & 1) * 16;
  const float* Brow = Wf + (size_t)(n0 + ar) * LORA;

  auto GLOADA = [&](int buf, int kt) {
    char* AsB = (char*)As[buf];
    gload16(A + (size_t)(m0 + r0) * LORA + kt + k0e, AsB + w * 1024);
    gload16(A + (size_t)(m0 + r1) * LORA + kt + k1e, AsB + 4096 + w * 1024);
  };
  f16x8 hb0, hb1;
  auto LOADB = [&](int kt) {
    const float* pb = Brow + kt + ac;
    f32x4 b0 = *(const f32x4*)(pb + 0), b1 = *(const f32x4*)(pb + 4);
    f32x4 b2 = *(const f32x4*)(pb + 8), b3 = *(const f32x4*)(pb + 12);
    hb0 = cvt8(b0, b1); hb1 = cvt8(b2, b3);
  };

  LOADB(0);
  GLOADA(0, 0);
  f32x4 acc[4][4] = {};

  for (int step = 0; step < 16; ++step) {
    const int cur = step & 1;
    *(f16x8*)&Bs[cur][ar * 32 + ac]     = hb0;
    *(f16x8*)&Bs[cur][ar * 32 + ac + 8] = hb1;
    __syncthreads();  // drains GLOADA(buf[cur]) issued one step ago
    if (step + 1 < 16) { LOADB((step + 1) * 32); GLOADA(cur ^ 1, (step + 1) * 32); }
    f16x8 af[4], bf[4];
#pragma unroll
    for (int im = 0; im < 4; ++im)
      af[im] = *(const f16x8*)&As[cur][(wr * 64 + im * 16 + (lane & 15)) * 32 + (lane >> 4) * 8];
#pragma unroll
    for (int in = 0; in < 4; ++in)
      bf[in] = *(const f16x8*)&Bs[cur][(wc * 64 + in * 16 + (lane & 15)) * 32 + (lane >> 4) * 8];
#pragma unroll
    for (int im = 0; im < 4; ++im)
#pragma unroll
      for (int in = 0; in < 4; ++in)
        acc[im][in] = __builtin_amdgcn_mfma_f32_16x16x32_f16(af[im], bf[in], acc[im][in], 0, 0, 0);
  }

#pragma unroll
  for (int im = 0; im < 4; ++im)
#pragma unroll
    for (int in = 0; in < 4; ++in)
#pragma unroll
      for (int j = 0; j < 4; ++j) {
        const int m = m0 + wr * 64 + im * 16 + (lane >> 4) * 4 + j;
        const int n = n0 + wc * 64 + in * 16 + (lane & 15);
        P[(size_t)m * HID + n] = (_Float16)acc[im][in][j];
      }
}

// ---------------------------------------------------------------------------
// K3: fused scores -> softmax sums -> block pooling -> expanded output.
// Double-buffered kv, single barrier per tile, loads overlapped with compute.
// pf shrunk to the 64-row window (scan early-exits).
// ---------------------------------------------------------------------------
__global__ __launch_bounds__(256) void attn_kernel(
    const _Float16* __restrict__ QP, const _Float16* __restrict__ KP,
    const float* __restrict__ bmask, const float* __restrict__ alphap,
    float* __restrict__ out)
{
  __shared__ float    bm[1024 * 4];      // [k][nb] mask
  __shared__ _Float16 kv[2][64 * 136];   // double-buffered K tile
  __shared__ float    pfq[64 * 4];       // causal-valid counts for this q-window
  __shared__ float    bs_l[64 * 4];      // [row][nb] alpha-scaled block scores

  const int t = threadIdx.x;
  const int lane = t & 63, w = t >> 6;
  const int bh = blockIdx.x, b = bh >> 5, h = bh & 31;
  const int qb = (int)(gridDim.y - 1) - (int)blockIdx.y;  // heavy blocks first

  for (int idx = t; idx < 4096; idx += 256) {
    const int nb = idx >> 10, k = idx & 1023;
    bm[k * 4 + nb] = bmask[(size_t)b * 4096 + idx];
  }
  __syncthreads();

  // wave-parallel inclusive prefix scan (wave w: nb=w), stop at seg qb
  {
    float carry = 0.f;
    for (int seg = 0; seg <= qb; ++seg) {
      float v = bm[(seg * 64 + lane) * 4 + w];
#pragma unroll
      for (int d = 1; d < 64; d <<= 1) {
        float u = __shfl_up(v, d, 64);
        if (lane >= d) v += u;
      }
      if (seg == qb) pfq[lane * 4 + w] = v + carry;
      carry += __shfl(v, 63, 64);
    }
  }

  const int qrow = qb * 64 + w * 16 + (lane & 15);
  const _Float16* qrp = QP + (size_t)(b * 1024 + qrow) * HID + h * DHEAD;
  f16x8 a[4];
#pragma unroll
  for (int i = 0; i < 4; ++i)
    a[i] = *(const f16x8*)(qrp + i * 32 + (lane >> 4) * 8);

  float bsum[4][4] = {};   // [nb][j]
  const float scale = 0.08838834764831845f;  // 1/sqrt(128)

  const int r = t >> 2, c = (t & 3) * 32;
  const _Float16* kbase = KP + (size_t)(b * 1024) * HID + h * DHEAD;

  f16x8 k0, k1, k2, k3;
  auto LOADK = [&](int kt) {
    const _Float16* pk = kbase + (size_t)(kt * 64 + r) * HID + c;
    k0 = *(const f16x8*)(pk + 0);
    k1 = *(const f16x8*)(pk + 8);
    k2 = *(const f16x8*)(pk + 16);
    k3 = *(const f16x8*)(pk + 24);
  };
  LOADK(0);

  for (int kt = 0; kt <= qb; ++kt) {
    const int cur = kt & 1;
    *(f16x8*)&kv[cur][r * 136 + c + 0]  = k0;
    *(f16x8*)&kv[cur][r * 136 + c + 8]  = k1;
    *(f16x8*)&kv[cur][r * 136 + c + 16] = k2;
    *(f16x8*)&kv[cur][r * 136 + c + 24] = k3;
    __syncthreads();
    if (kt < qb) LOADK(kt + 1);   // overlaps compute below

    const bool last = (kt == qb);
#pragma unroll
    for (int nt = 0; nt < 4; ++nt) {
      if (last && nt > w) break;   // fully-masked sub-tile (wave-uniform)
      f32x4 sacc = {0.f, 0.f, 0.f, 0.f};
#pragma unroll
      for (int i = 0; i < 4; ++i) {
        f16x8 bf = *(const f16x8*)&kv[cur][(nt * 16 + (lane & 15)) * 136 + i * 32 + (lane >> 4) * 8];
        sacc = __builtin_amdgcn_mfma_f32_16x16x32_f16(a[i], bf, sacc, 0, 0, 0);
      }
      const int kk = kt * 64 + nt * 16 + (lane & 15);
      f32x4 mv = *(const f32x4*)&bm[kk * 4];
      const bool diag = last && (nt == w);
#pragma unroll
      for (int j = 0; j < 4; ++j) {
        float e = __expf(sacc[j] * scale);
        if (diag) {
          const int q = qb * 64 + w * 16 + (lane >> 4) * 4 + j;
          e = (kk <= q) ? e : 0.f;
        }
        bsum[0][j] += e * mv[0];
        bsum[1][j] += e * mv[1];
        bsum[2][j] += e * mv[2];
        bsum[3][j] += e * mv[3];
      }
    }
  }

#pragma unroll
  for (int j = 0; j < 4; ++j)
#pragma unroll
    for (int m = 1; m < 16; m <<= 1)
#pragma unroll
      for (int nb = 0; nb < 4; ++nb)
        bsum[nb][j] += __shfl_xor(bsum[nb][j], m, 64);

  const float alpha = alphap[0];
  if ((lane & 15) == 0) {
#pragma unroll
    for (int j = 0; j < 4; ++j) {
      const int rr = w * 16 + (lane >> 4) * 4 + j;
      const float Lr = bsum[0][j] + bsum[1][j] + bsum[2][j] + bsum[3][j];
      const float ainvL = alpha / Lr;
#pragma unroll
      for (int nb = 0; nb < 4; ++nb)
        bs_l[rr * 4 + nb] = bsum[nb][j] * ainvL / fmaxf(pfq[rr * 4 + nb], 1.f);
    }
  }
  __syncthreads();

  // expansion: masks hoisted ONCE into registers (loop-invariant across rr)
  const size_t obase = ((size_t)bh * 1024 + (size_t)qb * 64) * 1024;
  const int k0i = t * 4;
  f32x4 m0v = *(const f32x4*)&bm[(k0i + 0) * 4];
  f32x4 m1v = *(const f32x4*)&bm[(k0i + 1) * 4];
  f32x4 m2v = *(const f32x4*)&bm[(k0i + 2) * 4];
  f32x4 m3v = *(const f32x4*)&bm[(k0i + 3) * 4];
  for (int rr = 0; rr < 64; ++rr) {
    const int q = qb * 64 + rr;
    f32x4 bsv = *(const f32x4*)&bs_l[rr * 4];   // same addr all lanes: broadcast
    f32x4 o;
    o[0] = (k0i + 0 <= q) ? (bsv[0]*m0v[0] + bsv[1]*m0v[1] + bsv[2]*m0v[2] + bsv[3]*m0v[3]) : 0.f;
    o[1] = (k0i + 1 <= q) ? (bsv[0]*m1v[0] + bsv[1]*m1v[1] + bsv[2]*m1v[2] + bsv[3]*m1v[3]) : 0.f;
    o[2] = (k0i + 2 <= q) ? (bsv[0]*m2v[0] + bsv[1]*m2v[1] + bsv[2]*m2v[2] + bsv[3]*m2v[3]) : 0.f;
    o[3] = (k0i + 3 <= q) ? (bsv[0]*m3v[0] + bsv[1]*m3v[1] + bsv[2]*m3v[2] + bsv[3]*m3v[3]) : 0.f;
    *(f32x4*)(out + obase + (size_t)rr * 1024 + k0i) = o;
  }
}

extern "C" void kernel_launch(void* const* d_in, const int* in_sizes, int n_in,
                              void* d_out, int out_size, void* d_ws, size_t ws_size,
                              hipStream_t stream) {
  const float* q     = (const float*)d_in[0];
  const float* k     = (const float*)d_in[1];
  const float* Wqa   = (const float*)d_in[2];
  const float* Wqb   = (const float*)d_in[3];
  const float* Wka   = (const float*)d_in[4];
  const float* Wkb   = (const float*)d_in[5];
  const float* alpha = (const float*)d_in[6];
  const float* bmask = (const float*)d_in[7];
  float* out = (float*)d_out;

  _Float16* Uq = (_Float16*)d_ws;                     // [2048,512] f16
  _Float16* Uk = Uq + (size_t)MROWS * LORA;
  _Float16* Pq = Uk + (size_t)MROWS * LORA;           // [2048,4096] f16
  _Float16* Pk = Pq + (size_t)MROWS * HID;
  float*    Up = (float*)(Pk + (size_t)MROWS * HID);  // [2][4][2048,512] f32

  gemm1_kernel<<<dim3(16, 4, 8), 256, 0, stream>>>(q, Wqa, k, Wka, Up);
  reduce_u    <<<1024, 256, 0, stream>>>(Up, Uq, Uk);
  gemm2_kernel<<<dim3(16, 32, 2), 256, 0, stream>>>(Uq, Wqb, Uk, Wkb, Pq, Pk);
  attn_kernel <<<dim3(64, 16), 256, 0, stream>>>(Pq, Pk, bmask, alpha, out);
}

// Round 9
// 450.036 us; speedup vs baseline: 1.0369x; 1.0369x over previous
//
#include <hip/hip_runtime.h>
#include <hip/hip_bf16.h>

typedef float    f32x4 __attribute__((ext_vector_type(4)));
typedef _Float16 f16x8 __attribute__((ext_vector_type(8)));
typedef _Float16 f16x4 __attribute__((ext_vector_type(4)));
typedef unsigned int u32;

#define S_LEN 1024
#define NHEAD 32
#define DHEAD 128
#define HID   4096   // NHEAD*DHEAD
#define LORA  512    // H*R
#define MROWS 2048   // B*S

__device__ __forceinline__ void gload16(const void* g, const void* l) {
  __builtin_amdgcn_global_load_lds(
      (const __attribute__((address_space(1))) u32*)g,
      (__attribute__((address_space(3))) u32*)l, 16, 0, 0);
}

// plain RNE f32->f16 (v_cvt_f16_f32) — validated numerics
__device__ __forceinline__ f16x8 cvt8(f32x4 a, f32x4 b) {
  f16x8 r;
  r[0] = (_Float16)a[0]; r[1] = (_Float16)a[1];
  r[2] = (_Float16)a[2]; r[3] = (_Float16)a[3];
  r[4] = (_Float16)b[0]; r[5] = (_Float16)b[1];
  r[6] = (_Float16)b[2]; r[7] = (_Float16)b[3];
  return r;
}

// ---------------------------------------------------------------------------
// K0: convert the four weight matrices f32 -> f16 (33.5 MB total, ~8 us).
// Layouts preserved.  Enables global_load_lds B-operands in both GEMMs.
// ---------------------------------------------------------------------------
#define WCH 262144   // 8-elem chunks per tensor (2.1M elems each)

__global__ __launch_bounds__(256) void convertW_kernel(
    const float* __restrict__ Wqa, const float* __restrict__ Wka,
    const float* __restrict__ Wqb, const float* __restrict__ Wkb,
    _Float16* __restrict__ WaqH, _Float16* __restrict__ WakH,
    _Float16* __restrict__ WbqH, _Float16* __restrict__ WbkH)
{
  const float* Ws[4] = {Wqa, Wka, Wqb, Wkb};
  _Float16*    Wd[4] = {WaqH, WakH, WbqH, WbkH};
  for (int c = blockIdx.x * 256 + threadIdx.x; c < 4 * WCH; c += 1024 * 256) {
    const int seg = c >> 18;
    const int off = (c & (WCH - 1)) * 8;
    const float* src = Ws[seg] + off;
    f32x4 v0 = *(const f32x4*)(src + 0);
    f32x4 v1 = *(const f32x4*)(src + 4);
    *(f16x8*)(Wd[seg] + off) = cvt8(v0, v1);
  }
}

// ---------------------------------------------------------------------------
// K1: split-K GEMM  U_partial = X @ Wa^T.  A-side: f32 X gather-transposed,
// reg-staged + RNE cvt.  B-side: f16 Wa via global_load_lds (width 16).
// 128x128 tile, BK=32, dbuf LDS, ONE barrier per K-step.  z = side*4+ks.
// ---------------------------------------------------------------------------
__global__ __launch_bounds__(256) void gemm1_kernel(
    const float* __restrict__ Xq, const _Float16* __restrict__ WaqH,
    const float* __restrict__ Xk, const _Float16* __restrict__ WakH,
    float* __restrict__ Up)
{
  const int side = blockIdx.z >> 2, ks = blockIdx.z & 3;
  const float* X = side ? Xk : Xq;
  const _Float16* WH = side ? WakH : WaqH;
  float* U = Up + ((size_t)(side * 4 + ks)) * (MROWS * LORA);

  __shared__ _Float16 As[2][128 * 32];
  __shared__ _Float16 Bs[2][128 * 32];

  const int t = threadIdx.x, lane = t & 63, w = t >> 6;
  const int wr = w >> 1, wc = w & 1;
  const int m0 = blockIdx.x * 128, n0 = blockIdx.y * 128;
  const int kbeg = ks * 1024;

  // A reg-staging map: thread -> (row ar, 16 cols at ac)
  const int ar = t >> 1, ac = (t & 1) * 16;
  const int am = m0 + ar, ab = am >> 10, as_ = am & 1023;
  const float* Abase = X + (size_t)ab * (NHEAD * S_LEN * DHEAD) + (size_t)as_ * DHEAD;

  // B gload slots (16B x2 per thread across the 8 KB tile)
  const int o0 = w * 1024 + lane * 16;
  const int o1 = o0 + 4096;
  const int r0 = o0 >> 6, k0e = (o0 & 63) >> 1;
  const int r1 = o1 >> 6, k1e = (o1 & 63) >> 1;

  auto GLOADB = [&](int buf, int kt) {
    char* BsB = (char*)Bs[buf];
    gload16(WH + (size_t)(n0 + r0) * HID + kt + k0e, BsB + w * 1024);
    gload16(WH + (size_t)(n0 + r1) * HID + kt + k1e, BsB + 4096 + w * 1024);
  };
  f16x8 ha0, ha1;
  auto LOADA = [&](int kt) {
    const int kg = kt + ac;
    const float* pa = Abase + (size_t)(kg >> 7) * (S_LEN * DHEAD) + (kg & 127);
    f32x4 a0 = *(const f32x4*)(pa + 0), a1 = *(const f32x4*)(pa + 4);
    f32x4 a2 = *(const f32x4*)(pa + 8), a3 = *(const f32x4*)(pa + 12);
    ha0 = cvt8(a0, a1); ha1 = cvt8(a2, a3);
  };

  GLOADB(0, kbeg);
  LOADA(kbeg);
  f32x4 acc[4][4] = {};

  for (int step = 0; step < 32; ++step) {
    const int cur = step & 1;
    *(f16x8*)&As[cur][ar * 32 + ac]     = ha0;
    *(f16x8*)&As[cur][ar * 32 + ac + 8] = ha1;
    __syncthreads();  // drains GLOADB(cur) + As writes; prior readers of buf cur^1 done
    if (step + 1 < 32) { GLOADB(cur ^ 1, kbeg + (step + 1) * 32); LOADA(kbeg + (step + 1) * 32); }
    f16x8 af[4], bf[4];
#pragma unroll
    for (int im = 0; im < 4; ++im)
      af[im] = *(const f16x8*)&As[cur][(wr * 64 + im * 16 + (lane & 15)) * 32 + (lane >> 4) * 8];
#pragma unroll
    for (int in = 0; in < 4; ++in)
      bf[in] = *(const f16x8*)&Bs[cur][(wc * 64 + in * 16 + (lane & 15)) * 32 + (lane >> 4) * 8];
#pragma unroll
    for (int im = 0; im < 4; ++im)
#pragma unroll
      for (int in = 0; in < 4; ++in)
        acc[im][in] = __builtin_amdgcn_mfma_f32_16x16x32_f16(af[im], bf[in], acc[im][in], 0, 0, 0);
  }

#pragma unroll
  for (int im = 0; im < 4; ++im)
#pragma unroll
    for (int in = 0; in < 4; ++in)
#pragma unroll
      for (int j = 0; j < 4; ++j) {
        const int m = m0 + wr * 64 + im * 16 + (lane >> 4) * 4 + j;
        const int n = n0 + wc * 64 + in * 16 + (lane & 15);
        U[(size_t)m * LORA + n] = acc[im][in][j];
      }
}

// ---------------------------------------------------------------------------
// K1b: reduce 4 f32 partials -> f16 U.
// ---------------------------------------------------------------------------
__global__ __launch_bounds__(256) void reduce_u(
    const float* __restrict__ Up, _Float16* __restrict__ Uq, _Float16* __restrict__ Uk)
{
  const int idx = blockIdx.x * 256 + threadIdx.x;   // 8-elem chunk
  const int side = idx >> 17;
  const int cc = idx & 131071;
  const float* base = Up + (size_t)side * 4 * (MROWS * LORA) + (size_t)cc * 8;
  f32x4 s0 = {0.f,0.f,0.f,0.f}, s1 = {0.f,0.f,0.f,0.f};
#pragma unroll
  for (int p = 0; p < 4; ++p) {
    const float* pp = base + (size_t)p * (MROWS * LORA);
    s0 += *(const f32x4*)(pp);
    s1 += *(const f32x4*)(pp + 4);
  }
  f16x8 h;
#pragma unroll
  for (int i = 0; i < 4; ++i) { h[i] = (_Float16)s0[i]; h[i + 4] = (_Float16)s1[i]; }
  _Float16* U = side ? Uk : Uq;
  *(f16x8*)(U + (size_t)cc * 8) = h;
}

// ---------------------------------------------------------------------------
// K2: P = U @ Wb^T, both operands f16 via global_load_lds (pure m97
// structure).  Single barrier per K-step, double-buffered.
// ---------------------------------------------------------------------------
__global__ __launch_bounds__(256) void gemm2_kernel(
    const _Float16* __restrict__ Uq, const _Float16* __restrict__ WbqH,
    const _Float16* __restrict__ Uk, const _Float16* __restrict__ WbkH,
    _Float16* __restrict__ Pq, _Float16* __restrict__ Pk)
{
  const _Float16* A = blockIdx.z ? Uk : Uq;
  const _Float16* B = blockIdx.z ? WbkH : WbqH;
  _Float16*       P = blockIdx.z ? Pk : Pq;

  __shared__ _Float16 As[2][128 * 32];
  __shared__ _Float16 Bs[2][128 * 32];

  const int t = threadIdx.x, lane = t & 63, w = t >> 6;
  const int wr = w >> 1, wc = w & 1;
  const int m0 = blockIdx.x * 128, n0 = blockIdx.y * 128;

  const int o0 = w * 1024 + lane * 16;
  const int o1 = o0 + 4096;
  const int r0 = o0 >> 6, k0e = (o0 & 63) >> 1;
  const int r1 = o1 >> 6, k1e = (o1 & 63) >> 1;

  auto GLOADAB = [&](int buf, int kt) {
    char* AsB = (char*)As[buf];
    char* BsB = (char*)Bs[buf];
    gload16(A + (size_t)(m0 + r0) * LORA + kt + k0e, AsB + w * 1024);
    gload16(A + (size_t)(m0 + r1) * LORA + kt + k1e, AsB + 4096 + w * 1024);
    gload16(B + (size_t)(n0 + r0) * LORA + kt + k0e, BsB + w * 1024);
    gload16(B + (size_t)(n0 + r1) * LORA + kt + k1e, BsB + 4096 + w * 1024);
  };

  GLOADAB(0, 0);
  f32x4 acc[4][4] = {};

  for (int step = 0; step < 16; ++step) {
    const int cur = step & 1;
    __syncthreads();  // drains gloads into buf cur; prior readers of cur^1 done
    if (step + 1 < 16) GLOADAB(cur ^ 1, (step + 1) * 32);
    f16x8 af[4], bf[4];
#pragma unroll
    for (int im = 0; im < 4; ++im)
      af[im] = *(const f16x8*)&As[cur][(wr * 64 + im * 16 + (lane & 15)) * 32 + (lane >> 4) * 8];
#pragma unroll
    for (int in = 0; in < 4; ++in)
      bf[in] = *(const f16x8*)&Bs[cur][(wc * 64 + in * 16 + (lane & 15)) * 32 + (lane >> 4) * 8];
#pragma unroll
    for (int im = 0; im < 4; ++im)
#pragma unroll
      for (int in = 0; in < 4; ++in)
        acc[im][in] = __builtin_amdgcn_mfma_f32_16x16x32_f16(af[im], bf[in], acc[im][in], 0, 0, 0);
  }

#pragma unroll
  for (int im = 0; im < 4; ++im)
#pragma unroll
    for (int in = 0; in < 4; ++in)
#pragma unroll
      for (int j = 0; j < 4; ++j) {
        const int m = m0 + wr * 64 + im * 16 + (lane >> 4) * 4 + j;
        const int n = n0 + wc * 64 + in * 16 + (lane & 15);
        P[(size_t)m * HID + n] = (_Float16)acc[im][in][j];
      }
}

// ---------------------------------------------------------------------------
// K3: fused scores -> softmax sums -> block pooling -> expanded output.
// Mask stored in LDS as f16 (exact for 0/1) -> 44 KB LDS -> 3 blocks/CU.
// Double-buffered kv, single barrier per tile.
// ---------------------------------------------------------------------------
__global__ __launch_bounds__(256) void attn_kernel(
    const _Float16* __restrict__ QP, const _Float16* __restrict__ KP,
    const float* __restrict__ bmask, const float* __restrict__ alphap,
    float* __restrict__ out)
{
  __shared__ _Float16 bm_h[1024 * 4];    // [k][nb] mask (f16, exact 0/1)
  __shared__ _Float16 kv[2][64 * 136];   // double-buffered K tile
  __shared__ float    pfq[64 * 4];       // causal-valid counts for this q-window
  __shared__ float    bs_l[64 * 4];      // [row][nb] alpha-scaled block scores

  const int t = threadIdx.x;
  const int lane = t & 63, w = t >> 6;
  const int bh = blockIdx.x, b = bh >> 5, h = bh & 31;
  const int qb = (int)(gridDim.y - 1) - (int)blockIdx.y;  // heavy blocks first

  for (int idx = t; idx < 4096; idx += 256) {
    const int nb = idx >> 10, k = idx & 1023;
    bm_h[k * 4 + nb] = (_Float16)bmask[(size_t)b * 4096 + idx];
  }
  __syncthreads();

  // wave-parallel inclusive prefix scan (wave w: nb=w), stop at seg qb
  {
    float carry = 0.f;
    for (int seg = 0; seg <= qb; ++seg) {
      float v = (float)bm_h[(seg * 64 + lane) * 4 + w];
#pragma unroll
      for (int d = 1; d < 64; d <<= 1) {
        float u = __shfl_up(v, d, 64);
        if (lane >= d) v += u;
      }
      if (seg == qb) pfq[lane * 4 + w] = v + carry;
      carry += __shfl(v, 63, 64);
    }
  }

  const int qrow = qb * 64 + w * 16 + (lane & 15);
  const _Float16* qrp = QP + (size_t)(b * 1024 + qrow) * HID + h * DHEAD;
  f16x8 a[4];
#pragma unroll
  for (int i = 0; i < 4; ++i)
    a[i] = *(const f16x8*)(qrp + i * 32 + (lane >> 4) * 8);

  float bsum[4][4] = {};   // [nb][j]
  const float scale = 0.08838834764831845f;  // 1/sqrt(128)

  const int r = t >> 2, c = (t & 3) * 32;
  const _Float16* kbase = KP + (size_t)(b * 1024) * HID + h * DHEAD;

  f16x8 k0, k1, k2, k3;
  auto LOADK = [&](int kt) {
    const _Float16* pk = kbase + (size_t)(kt * 64 + r) * HID + c;
    k0 = *(const f16x8*)(pk + 0);
    k1 = *(const f16x8*)(pk + 8);
    k2 = *(const f16x8*)(pk + 16);
    k3 = *(const f16x8*)(pk + 24);
  };
  LOADK(0);

  for (int kt = 0; kt <= qb; ++kt) {
    const int cur = kt & 1;
    *(f16x8*)&kv[cur][r * 136 + c + 0]  = k0;
    *(f16x8*)&kv[cur][r * 136 + c + 8]  = k1;
    *(f16x8*)&kv[cur][r * 136 + c + 16] = k2;
    *(f16x8*)&kv[cur][r * 136 + c + 24] = k3;
    __syncthreads();
    if (kt < qb) LOADK(kt + 1);   // overlaps compute below

    const bool last = (kt == qb);
#pragma unroll
    for (int nt = 0; nt < 4; ++nt) {
      if (last && nt > w) break;   // fully-masked sub-tile (wave-uniform)
      f32x4 sacc = {0.f, 0.f, 0.f, 0.f};
#pragma unroll
      for (int i = 0; i < 4; ++i) {
        f16x8 bf = *(const f16x8*)&kv[cur][(nt * 16 + (lane & 15)) * 136 + i * 32 + (lane >> 4) * 8];
        sacc = __builtin_amdgcn_mfma_f32_16x16x32_f16(a[i], bf, sacc, 0, 0, 0);
      }
      const int kk = kt * 64 + nt * 16 + (lane & 15);
      const f16x4 mh = *(const f16x4*)&bm_h[kk * 4];
      const float mv0 = (float)mh[0], mv1 = (float)mh[1];
      const float mv2 = (float)mh[2], mv3 = (float)mh[3];
      const bool diag = last && (nt == w);
#pragma unroll
      for (int j = 0; j < 4; ++j) {
        float e = __expf(sacc[j] * scale);
        if (diag) {
          const int q = qb * 64 + w * 16 + (lane >> 4) * 4 + j;
          e = (kk <= q) ? e : 0.f;
        }
        bsum[0][j] += e * mv0;
        bsum[1][j] += e * mv1;
        bsum[2][j] += e * mv2;
        bsum[3][j] += e * mv3;
      }
    }
  }

#pragma unroll
  for (int j = 0; j < 4; ++j)
#pragma unroll
    for (int m = 1; m < 16; m <<= 1)
#pragma unroll
      for (int nb = 0; nb < 4; ++nb)
        bsum[nb][j] += __shfl_xor(bsum[nb][j], m, 64);

  const float alpha = alphap[0];
  if ((lane & 15) == 0) {
#pragma unroll
    for (int j = 0; j < 4; ++j) {
      const int rr = w * 16 + (lane >> 4) * 4 + j;
      const float Lr = bsum[0][j] + bsum[1][j] + bsum[2][j] + bsum[3][j];
      const float ainvL = alpha / Lr;
#pragma unroll
      for (int nb = 0; nb < 4; ++nb)
        bs_l[rr * 4 + nb] = bsum[nb][j] * ainvL / fmaxf(pfq[rr * 4 + nb], 1.f);
    }
  }
  __syncthreads();

  // expansion: masks hoisted ONCE into registers (loop-invariant across rr)
  const size_t obase = ((size_t)bh * 1024 + (size_t)qb * 64) * 1024;
  const int k0i = t * 4;
  f32x4 mv[4];
#pragma unroll
  for (int i = 0; i < 4; ++i) {
    const f16x4 mh = *(const f16x4*)&bm_h[(k0i + i) * 4];
    mv[i][0] = (float)mh[0]; mv[i][1] = (float)mh[1];
    mv[i][2] = (float)mh[2]; mv[i][3] = (float)mh[3];
  }
  for (int rr = 0; rr < 64; ++rr) {
    const int q = qb * 64 + rr;
    f32x4 bsv = *(const f32x4*)&bs_l[rr * 4];   // same addr all lanes: broadcast
    f32x4 o;
#pragma unroll
    for (int i = 0; i < 4; ++i)
      o[i] = (k0i + i <= q)
           ? (bsv[0]*mv[i][0] + bsv[1]*mv[i][1] + bsv[2]*mv[i][2] + bsv[3]*mv[i][3]) : 0.f;
    *(f32x4*)(out + obase + (size_t)rr * 1024 + k0i) = o;
  }
}

extern "C" void kernel_launch(void* const* d_in, const int* in_sizes, int n_in,
                              void* d_out, int out_size, void* d_ws, size_t ws_size,
                              hipStream_t stream) {
  const float* q     = (const float*)d_in[0];
  const float* k     = (const float*)d_in[1];
  const float* Wqa   = (const float*)d_in[2];
  const float* Wqb   = (const float*)d_in[3];
  const float* Wka   = (const float*)d_in[4];
  const float* Wkb   = (const float*)d_in[5];
  const float* alpha = (const float*)d_in[6];
  const float* bmask = (const float*)d_in[7];
  float* out = (float*)d_out;

  _Float16* WaqH = (_Float16*)d_ws;                   // [512,4096] f16
  _Float16* WakH = WaqH + (size_t)LORA * HID;
  _Float16* WbqH = WakH + (size_t)LORA * HID;         // [4096,512] f16
  _Float16* WbkH = WbqH + (size_t)HID * LORA;
  _Float16* Uq   = WbkH + (size_t)HID * LORA;         // [2048,512] f16
  _Float16* Uk   = Uq   + (size_t)MROWS * LORA;
  _Float16* Pq   = Uk   + (size_t)MROWS * LORA;       // [2048,4096] f16
  _Float16* Pk   = Pq   + (size_t)MROWS * HID;
  float*    Up   = (float*)(Pk + (size_t)MROWS * HID);  // [2][4][2048,512] f32

  convertW_kernel<<<1024, 256, 0, stream>>>(Wqa, Wka, Wqb, Wkb, WaqH, WakH, WbqH, WbkH);
  gemm1_kernel<<<dim3(16, 4, 8), 256, 0, stream>>>(q, WaqH, k, WakH, Up);
  reduce_u    <<<1024, 256, 0, stream>>>(Up, Uq, Uk);
  gemm2_kernel<<<dim3(16, 32, 2), 256, 0, stream>>>(Uq, WbqH, Uk, WbkH, Pq, Pk);
  attn_kernel <<<dim3(64, 16), 256, 0, stream>>>(Pq, Pk, bmask, alpha, out);
}